// Round 1
// baseline (333.827 us; speedup 1.0000x reference)
//
#include <hip/hip_runtime.h>
#include <hip/hip_bf16.h>

// Problem constants
#define B_    8
#define N_    256
#define DN_   16
#define DE_   8
#define H_    64
#define Z_    64
#define L_    3
#define FC_   128
#define ROWS_ (B_ * N_)       // 2048
#define EDGES_ (B_ * N_ * N_) // 524288

__device__ __forceinline__ float fast_tanh(float x) {
    // tanh(x) = 1 - 2/(exp(2x)+1); exp via v_exp_f32, rcp via v_rcp_f32.
    float e = __expf(2.0f * x);
    return 1.0f - 2.0f * __builtin_amdgcn_rcpf(e + 1.0f);
}

// ---------------------------------------------------------------------------
// Kernel A: node embedding -> hcat segment 0.   nh = tanh(tanh(x@W1+b1)@W2+b2)
// one block (128 thr) per row
// ---------------------------------------------------------------------------
__global__ __launch_bounds__(128) void node_embed_kernel(
    const float* __restrict__ nf, const float* __restrict__ w1,
    const float* __restrict__ b1, const float* __restrict__ w2,
    const float* __restrict__ b2, float* __restrict__ hcat)
{
    int row = blockIdx.x;
    int t = threadIdx.x;
    __shared__ float x[DN_];
    __shared__ float hid[FC_];
    if (t < DN_) x[t] = nf[row * DN_ + t];
    __syncthreads();
    float a = b1[t];
#pragma unroll
    for (int c = 0; c < DN_; ++c) a += x[c] * w1[c * FC_ + t];
    hid[t] = fast_tanh(a);
    __syncthreads();
    if (t < H_) {
        float a2 = b2[t];
#pragma unroll
        for (int k = 0; k < FC_; ++k) a2 += hid[k] * w2[k * H_ + t];
        hcat[(size_t)row * 256 + t] = fast_tanh(a2);
    }
}

// ---------------------------------------------------------------------------
// Kernel B: edge MLP + channel sum  (dominant kernel, ~9.7 GFLOP)
// ehs[b,i,j] = sum_c tanh( tanh(ef[b,i,j,:]@W1+b1) @ W2 + b2 )[c]
// one thread per edge; weights are wave-uniform -> scalar loads; acc in VGPRs
// ---------------------------------------------------------------------------
__global__ __launch_bounds__(256) void edge_mlp_kernel(
    const float* __restrict__ ef, const float* __restrict__ w1,
    const float* __restrict__ b1, const float* __restrict__ w2,
    const float* __restrict__ b2, float* __restrict__ ehs)
{
    int e = blockIdx.x * 256 + threadIdx.x;
    const float4* ep = (const float4*)(ef + (size_t)e * DE_);
    float4 x0 = ep[0], x1 = ep[1];
    float x[8] = {x0.x, x0.y, x0.z, x0.w, x1.x, x1.y, x1.z, x1.w};
    float acc[H_];
#pragma unroll
    for (int o = 0; o < H_; ++o) acc[o] = b2[o];
    for (int k = 0; k < FC_; ++k) {
        float hk = b1[k];
#pragma unroll
        for (int c = 0; c < DE_; ++c) hk += x[c] * w1[c * FC_ + k];
        hk = fast_tanh(hk);
        const float* w2r = w2 + k * H_;
#pragma unroll
        for (int o = 0; o < H_; ++o) acc[o] += hk * w2r[o];
    }
    float s = 0.f;
#pragma unroll
    for (int o = 0; o < H_; ++o) s += fast_tanh(acc[o]);
    ehs[e] = s;
}

// ---------------------------------------------------------------------------
// Kernel C1 per layer: h = tanh( (adj @ hidden) @ gcn_w )   [associativity]
// one wave per row, 4 waves/block
// ---------------------------------------------------------------------------
__global__ __launch_bounds__(256) void gcn_kernel(
    const float* __restrict__ adj, const float* __restrict__ hcat,
    const float* __restrict__ gw, float* __restrict__ h, int seg)
{
    int wid = threadIdx.x >> 6;
    int lane = threadIdx.x & 63;
    int row = __builtin_amdgcn_readfirstlane(blockIdx.x * 4 + wid);
    int b = row >> 8;
    const float* arow = adj + (size_t)row * N_;
    const float* hb = hcat + (size_t)b * N_ * 256 + seg * H_;
    float g = 0.f;
    for (int j = 0; j < N_; ++j) g += arow[j] * hb[j * 256 + lane];
    __shared__ float gs[4][H_];
    gs[wid][lane] = g;
    __syncthreads();
    float a = 0.f;
#pragma unroll
    for (int k = 0; k < H_; ++k) a += gs[wid][k] * gw[k * H_ + lane];
    h[(size_t)row * H_ + lane] = fast_tanh(a);
}

// ---------------------------------------------------------------------------
// Kernel C2 per layer: comb = tanh(ehs @ h);
// hidden' = tanh([h, comb] @ comb_w + comb_b) -> hcat segment seg+1
// ---------------------------------------------------------------------------
__global__ __launch_bounds__(256) void comb_kernel(
    const float* __restrict__ ehs, const float* __restrict__ h,
    const float* __restrict__ cw, const float* __restrict__ cb,
    float* __restrict__ hcat, int seg)
{
    int wid = threadIdx.x >> 6;
    int lane = threadIdx.x & 63;
    int row = __builtin_amdgcn_readfirstlane(blockIdx.x * 4 + wid);
    int b = row >> 8;
    const float* er = ehs + (size_t)row * N_;
    const float* hb = h + (size_t)b * N_ * H_;
    float c = 0.f;
    for (int j = 0; j < N_; ++j) c += er[j] * hb[j * H_ + lane];
    c = fast_tanh(c);
    __shared__ float ch[4][H_], hi[4][H_];
    ch[wid][lane] = c;
    hi[wid][lane] = h[(size_t)row * H_ + lane];
    __syncthreads();
    float a = cb[lane];
#pragma unroll
    for (int k = 0; k < H_; ++k) a += hi[wid][k] * cw[k * H_ + lane];
#pragma unroll
    for (int k = 0; k < H_; ++k) a += ch[wid][k] * cw[(H_ + k) * H_ + lane];
    hcat[(size_t)row * 256 + (seg + 1) * H_ + lane] = fast_tanh(a);
}

// ---------------------------------------------------------------------------
// Kernel D: mean / logvar heads + latent.  G=8 rows per block amortizes the
// 256 KB of head weights across rows (weight traffic /8).
// out layout: [latent | mean | logvar], each B*N*Z floats.
// ---------------------------------------------------------------------------
__global__ __launch_bounds__(128) void head_kernel(
    const float* __restrict__ hcat, const float* __restrict__ noise,
    const float* __restrict__ m1w, const float* __restrict__ m1b,
    const float* __restrict__ m2w, const float* __restrict__ m2b,
    const float* __restrict__ v1w, const float* __restrict__ v1b,
    const float* __restrict__ v2w, const float* __restrict__ v2b,
    float* __restrict__ out)
{
    const int G = 8;
    int row0 = blockIdx.x * G;
    int t = threadIdx.x;
    __shared__ float rbT[256][G];  // transposed row tiles: rbT[k][g]
    __shared__ float hid[G][FC_];
    __shared__ float ms[G][H_];
    for (int idx = t; idx < 256 * G; idx += 128) {
        int k = idx >> 3, g = idx & 7;
        rbT[k][g] = hcat[(size_t)(row0 + g) * 256 + k];
    }
    __syncthreads();

    // ----- mean head: hidden -----
    float acc[G];
#pragma unroll
    for (int g = 0; g < G; ++g) acc[g] = m1b[t];
    for (int k = 0; k < 256; ++k) {
        float w = m1w[k * FC_ + t];
        const float4* rp = (const float4*)&rbT[k][0];
        float4 r0 = rp[0], r1 = rp[1];
        acc[0] += r0.x * w; acc[1] += r0.y * w; acc[2] += r0.z * w; acc[3] += r0.w * w;
        acc[4] += r1.x * w; acc[5] += r1.y * w; acc[6] += r1.z * w; acc[7] += r1.w * w;
    }
#pragma unroll
    for (int g = 0; g < G; ++g) hid[g][t] = fast_tanh(acc[g]);
    __syncthreads();
    if (t < H_) {
#pragma unroll
        for (int g = 0; g < G; ++g) {
            float m = m2b[t];
            for (int k = 0; k < FC_; ++k) m += hid[g][k] * m2w[k * H_ + t];
            ms[g][t] = m;
            out[(size_t)ROWS_ * Z_ + (size_t)(row0 + g) * H_ + t] = m;
        }
    }
    __syncthreads();

    // ----- logvar head (reuse hid) -----
#pragma unroll
    for (int g = 0; g < G; ++g) acc[g] = v1b[t];
    for (int k = 0; k < 256; ++k) {
        float w = v1w[k * FC_ + t];
        const float4* rp = (const float4*)&rbT[k][0];
        float4 r0 = rp[0], r1 = rp[1];
        acc[0] += r0.x * w; acc[1] += r0.y * w; acc[2] += r0.z * w; acc[3] += r0.w * w;
        acc[4] += r1.x * w; acc[5] += r1.y * w; acc[6] += r1.z * w; acc[7] += r1.w * w;
    }
#pragma unroll
    for (int g = 0; g < G; ++g) hid[g][t] = fast_tanh(acc[g]);
    __syncthreads();
    if (t < H_) {
#pragma unroll
        for (int g = 0; g < G; ++g) {
            float lv = v2b[t];
            for (int k = 0; k < FC_; ++k) lv += hid[g][k] * v2w[k * H_ + t];
            out[(size_t)2 * ROWS_ * Z_ + (size_t)(row0 + g) * H_ + t] = lv;
            float lat = noise[(size_t)(row0 + g) * H_ + t] * __expf(0.5f * lv) + ms[g][t];
            out[(size_t)(row0 + g) * H_ + t] = lat;
        }
    }
}

extern "C" void kernel_launch(void* const* d_in, const int* in_sizes, int n_in,
                              void* d_out, int out_size, void* d_ws, size_t ws_size,
                              hipStream_t stream)
{
    const float* adj   = (const float*)d_in[0];
    const float* nf    = (const float*)d_in[1];
    const float* ef    = (const float*)d_in[2];
    const float* noise = (const float*)d_in[3];
    const float* nw1 = (const float*)d_in[4];  const float* nb1 = (const float*)d_in[5];
    const float* nw2 = (const float*)d_in[6];  const float* nb2 = (const float*)d_in[7];
    const float* ew1 = (const float*)d_in[8];  const float* eb1 = (const float*)d_in[9];
    const float* ew2 = (const float*)d_in[10]; const float* eb2 = (const float*)d_in[11];
    const float* gw  = (const float*)d_in[12];
    const float* cw  = (const float*)d_in[13]; const float* cb = (const float*)d_in[14];
    const float* m1w = (const float*)d_in[15]; const float* m1b = (const float*)d_in[16];
    const float* m2w = (const float*)d_in[17]; const float* m2b = (const float*)d_in[18];
    const float* v1w = (const float*)d_in[19]; const float* v1b = (const float*)d_in[20];
    const float* v2w = (const float*)d_in[21]; const float* v2b = (const float*)d_in[22];

    float* out  = (float*)d_out;
    float* ws   = (float*)d_ws;
    float* hcat = ws;                 // ROWS_*256   = 524288 floats
    float* ehs  = ws + 524288;        // B*N*N       = 524288 floats
    float* h    = ws + 1048576;       // ROWS_*H     = 131072 floats

    hipLaunchKernelGGL(node_embed_kernel, dim3(ROWS_), dim3(128), 0, stream,
                       nf, nw1, nb1, nw2, nb2, hcat);
    hipLaunchKernelGGL(edge_mlp_kernel, dim3(EDGES_ / 256), dim3(256), 0, stream,
                       ef, ew1, eb1, ew2, eb2, ehs);
    for (int l = 0; l < L_; ++l) {
        hipLaunchKernelGGL(gcn_kernel, dim3(ROWS_ / 4), dim3(256), 0, stream,
                           adj, hcat, gw + l * H_ * H_, h, l);
        hipLaunchKernelGGL(comb_kernel, dim3(ROWS_ / 4), dim3(256), 0, stream,
                           ehs, h, cw + l * 2 * H_ * H_, cb + l * H_, hcat, l);
    }
    hipLaunchKernelGGL(head_kernel, dim3(ROWS_ / 8), dim3(128), 0, stream,
                       hcat, noise, m1w, m1b, m2w, m2b, v1w, v1b, v2w, v2b, out);
}